// Round 5
// baseline (375.095 us; speedup 1.0000x reference)
//
#include <hip/hip_runtime.h>

// VGRUd v5 — role-split waves, pre-split h in LDS, light barriers.
// 512 blocks x 512 thr (8 waves), 64 rows/block, 2 blocks/CU (57344 B LDS).
// Waves 0..3 (logits): rows w*16..+16: Wd-hi persistent in VGPR, wd-lo streamed
//   from LDS; softmax (no max-sub, clamp 80) via DPP row_ror; probs stores.
// Waves 4..7 (gates): jt=w-4 col-slice, all 64 rows; gate weights persistent in
//   VGPR (64); h_prev for own C-positions in registers (no re-read).
// h stored PRE-SPLIT (hi/lo bf16 planes, stride 72 ush = 16B-aligned,
//   conflict-free) -> A-frags are raw ds_read_b128, zero split VALU per step.
// Barrier = s_waitcnt lgkmcnt(0) + s_barrier (NO vmcnt drain -> probs stores
//   pipeline across steps). 1 barrier/step, double-buffered h.
// Step 1 (K=192) fused via 6 staged K=32 chunks (gate-remapped [Wk;Uk]).

typedef short bf16x8 __attribute__((ext_vector_type(8)));
typedef float f32x4 __attribute__((ext_vector_type(4)));

#define TPB 512
#define HSTR 72

__device__ __forceinline__ float fsig(float x) {
  return __builtin_amdgcn_rcpf(1.0f + __expf(-x));
}
__device__ __forceinline__ float ftanh2(float x) {
  return 1.0f - 2.0f * __builtin_amdgcn_rcpf(__expf(2.0f * x) + 1.0f);
}
template <int CTRL>
__device__ __forceinline__ float dppror(float x) {
  return __int_as_float(
      __builtin_amdgcn_update_dpp(0, __float_as_int(x), CTRL, 0xf, 0xf, true));
}
__device__ __forceinline__ unsigned pack_hi16(float a, float b) {
  return __builtin_amdgcn_perm(__float_as_uint(b), __float_as_uint(a), 0x07060302u);
}
__device__ __forceinline__ float truncbf(float a) {
  return __uint_as_float(__float_as_uint(a) & 0xffff0000u);
}
__device__ __forceinline__ unsigned short bf16rne(float f) {
  unsigned u = __float_as_uint(f);
  return (unsigned short)((u + 0x7fffu + ((u >> 16) & 1u)) >> 16);
}
__device__ __forceinline__ void split8(const float f[8], bf16x8& ah, bf16x8& al) {
  uint4 ph, pl;
  ph.x = pack_hi16(f[0], f[1]); ph.y = pack_hi16(f[2], f[3]);
  ph.z = pack_hi16(f[4], f[5]); ph.w = pack_hi16(f[6], f[7]);
  pl.x = pack_hi16(f[0] - truncbf(f[0]), f[1] - truncbf(f[1]));
  pl.y = pack_hi16(f[2] - truncbf(f[2]), f[3] - truncbf(f[3]));
  pl.z = pack_hi16(f[4] - truncbf(f[4]), f[5] - truncbf(f[5]));
  pl.w = pack_hi16(f[6] - truncbf(f[6]), f[7] - truncbf(f[7]));
  ah = __builtin_bit_cast(bf16x8, ph);
  al = __builtin_bit_cast(bf16x8, pl);
}
__device__ __forceinline__ void light_barrier() {
  __builtin_amdgcn_sched_barrier(0);
  asm volatile("s_waitcnt lgkmcnt(0)" ::: "memory");
  __builtin_amdgcn_s_barrier();
  __builtin_amdgcn_sched_barrier(0);
}

#define MFMA __builtin_amdgcn_mfma_f32_16x16x32_bf16

__global__ __launch_bounds__(TPB, 4) void vgru_all(
    const float* __restrict__ x, const float* __restrict__ Hin,
    const float* __restrict__ Wk, const float* __restrict__ Uk,
    const float* __restrict__ bias, const float* __restrict__ Wd,
    const float* __restrict__ bd, float* __restrict__ out)
{
  extern __shared__ float smem[];
  float* wdHi  = smem;           // 2560 floats (10 frags hi)
  float* wdLo  = smem + 2560;    // 2560
  float* chkHi = smem + 5120;    // 4096 (step-1 only; aliases h)
  float* chkLo = smem + 9216;    // 4096
  unsigned short* hbase = (unsigned short*)(smem + 5120);
  // h buffer p (p=0,1): hi = hbase + p*9216 ([64][72] ush), lo = +4608

  const int tid  = threadIdx.x;
  const int lane = tid & 63, w = tid >> 6;
  const int g = lane >> 4, n = lane & 15;
  const bool islog = (w < 4);
  const int jt = w & 3;
  const int blockbase = blockIdx.x * 64;
  const float* b0 = bias;
  const float* b1 = bias + 192;

  // ---- stage Wd frags (hi/lo planes) ----
  for (int idx = tid; idx < 640; idx += TPB) {
    int fr = idx >> 6, ln = idx & 63;
    int nt = fr >> 1, ks = fr & 1;
    int lg = ln >> 4, lnn = ln & 15;
    int c = nt * 16 + lnn;
    float f[8];
    #pragma unroll
    for (int j = 0; j < 8; ++j) {
      int k = ks * 32 + lg * 8 + j;
      f[j] = (c < 78) ? Wd[k * 78 + c] : 0.0f;
    }
    bf16x8 h8, l8; split8(f, h8, l8);
    ((bf16x8*)wdHi)[fr * 64 + ln] = h8;
    ((bf16x8*)wdLo)[fr * 64 + ln] = l8;
  }

  // gate biases (valid for gates waves; harmless otherwise)
  const int cb = jt * 16 + n;
  const float bz  = b0[cb] + b1[cb];
  const float brr = b0[64 + cb] + b1[64 + cb];
  const float bxh = b0[128 + cb];
  const float bhh = b1[128 + cb];

  // ---- step 1: h1 = gru(x, H), K=192 in 6 chunks of K=32 ----
  f32x4 G0[4][4];  // [mt][gate]
  if (!islog) {
    #pragma unroll
    for (int mt = 0; mt < 4; ++mt) {
      G0[mt][0] = (f32x4){bz, bz, bz, bz};
      G0[mt][1] = (f32x4){brr, brr, brr, brr};
      G0[mt][2] = (f32x4){bxh, bxh, bxh, bxh};
      G0[mt][3] = (f32x4){bhh, bhh, bhh, bhh};
    }
  }

  for (int t = 0; t < 6; ++t) {
    // stage chunk: stacked [Wk;Uk] rows t*32..+32, gate-remapped cols
    for (int idx = tid; idx < 1024; idx += TPB) {
      int fr = idx >> 6, ln = idx & 63;      // fr = col-tile 0..15
      int lg = ln >> 4, lnn = ln & 15;
      int c = fr * 16 + lnn;
      float f[8];
      #pragma unroll
      for (int j = 0; j < 8; ++j) {
        int k = t * 32 + lg * 8 + j;
        float v;
        if (k < 128) v = (c < 192) ? Wk[k * 192 + c] : 0.0f;
        else {
          int ku = k - 128;
          v = (c < 128) ? Uk[ku * 192 + c]
                        : ((c < 192) ? 0.0f : Uk[ku * 192 + 128 + (c - 192)]);
        }
        f[j] = v;
      }
      bf16x8 h8, l8; split8(f, h8, l8);
      ((bf16x8*)chkHi)[fr * 64 + ln] = h8;
      ((bf16x8*)chkLo)[fr * 64 + ln] = l8;
    }
    __syncthreads();
    if (!islog) {
      bf16x8 Ah[4], Al[4];
      #pragma unroll
      for (int mt = 0; mt < 4; ++mt) {
        const float* src = (t < 4)
            ? x + (size_t)(blockbase + mt * 16 + n) * 128 + t * 32 + g * 8
            : Hin + (size_t)(blockbase + mt * 16 + n) * 64 + (t - 4) * 32 + g * 8;
        float4 v0 = *(const float4*)src;
        float4 v1 = *(const float4*)(src + 4);
        float f[8] = {v0.x, v0.y, v0.z, v0.w, v1.x, v1.y, v1.z, v1.w};
        split8(f, Ah[mt], Al[mt]);
      }
      #pragma unroll
      for (int gg = 0; gg < 4; ++gg) {
        int ntb = gg * 4 + jt;
        bf16x8 wh = ((const bf16x8*)chkHi)[ntb * 64 + lane];
        bf16x8 wl = ((const bf16x8*)chkLo)[ntb * 64 + lane];
        #pragma unroll
        for (int mt = 0; mt < 4; ++mt) {
          G0[mt][gg] = MFMA(Ah[mt], wh, G0[mt][gg], 0, 0, 0);
          G0[mt][gg] = MFMA(Al[mt], wh, G0[mt][gg], 0, 0, 0);
          G0[mt][gg] = MFMA(Ah[mt], wl, G0[mt][gg], 0, 0, 0);
        }
      }
    }
    __syncthreads();
  }

  // step-1 epilogue: gates waves write pre-split h1 into buffer 0 + hold regs
  float hold[16];
  {
    unsigned short* hAHi = hbase;
    unsigned short* hALo = hbase + 4608;
    if (!islog) {
      #pragma unroll
      for (int mt = 0; mt < 4; ++mt)
        #pragma unroll
        for (int rr = 0; rr < 4; ++rr) {
          int lrow = mt * 16 + g * 4 + rr;
          float h0 = Hin[(size_t)(blockbase + lrow) * 64 + cb];
          float z  = fsig(G0[mt][0][rr]);
          float rg = fsig(G0[mt][1][rr]);
          float cand = ftanh2(G0[mt][2][rr] + rg * G0[mt][3][rr]);
          float hv = cand + z * (h0 - cand);
          hold[mt * 4 + rr] = hv;
          unsigned u = __float_as_uint(hv);
          int widx = lrow * HSTR + cb;
          hAHi[widx] = (unsigned short)(u >> 16);
          hALo[widx] = bf16rne(hv - truncbf(hv));
        }
    }
  }

  // ---- persistent weights ----
  bf16x8 Wh[4][2], Wl[4][2];  // gates waves: combined gate matrix, jt slice
  bf16x8 wdh[5][2];           // logits waves: Wd hi frags
  float bdv[5];
  if (!islog) {
    #pragma unroll
    for (int gg = 0; gg < 4; ++gg)
      #pragma unroll
      for (int ks = 0; ks < 2; ++ks) {
        int c = (gg * 4 + jt) * 16 + n;
        float f[8];
        #pragma unroll
        for (int j = 0; j < 8; ++j) {
          int k = ks * 32 + g * 8 + j;
          float v;
          if      (c < 128) v = Wk[k * 192 + c] + Uk[k * 192 + c];
          else if (c < 192) v = Wk[k * 192 + c];
          else              v = Uk[k * 192 + 128 + (c - 192)];
          f[j] = v;
        }
        split8(f, Wh[gg][ks], Wl[gg][ks]);
      }
  } else {
    #pragma unroll
    for (int nt = 0; nt < 5; ++nt) {
      #pragma unroll
      for (int ks = 0; ks < 2; ++ks)
        wdh[nt][ks] = ((const bf16x8*)wdHi)[(nt * 2 + ks) * 64 + lane];
      int c = nt * 16 + n;
      bdv[nt] = (c < 78) ? bd[c] : 0.0f;
    }
  }
  __syncthreads();

  // ---- 25 iterations ----
  #pragma unroll 1
  for (int s = 0; s < 25; ++s) {
    const unsigned short* curHi = hbase + (s & 1) * 9216;
    const unsigned short* curLo = curHi + 4608;
    unsigned short* nxtHi = hbase + ((s + 1) & 1) * 9216;
    unsigned short* nxtLo = nxtHi + 4608;

    if (islog) {
      // logits for rows w*16..+16 of cur
      bf16x8 Ah[2], Al[2];
      #pragma unroll
      for (int ks = 0; ks < 2; ++ks) {
        Ah[ks] = *(const bf16x8*)(curHi + (w * 16 + n) * HSTR + ks * 32 + g * 8);
        Al[ks] = *(const bf16x8*)(curLo + (w * 16 + n) * HSTR + ks * 32 + g * 8);
      }
      f32x4 L[5];
      #pragma unroll
      for (int nt = 0; nt < 5; ++nt)
        L[nt] = (f32x4){bdv[nt], bdv[nt], bdv[nt], bdv[nt]};
      #pragma unroll
      for (int nt = 0; nt < 5; ++nt)
        #pragma unroll
        for (int ks = 0; ks < 2; ++ks) {
          bf16x8 wl = ((const bf16x8*)wdLo)[(nt * 2 + ks) * 64 + lane];
          L[nt] = MFMA(Ah[ks], wdh[nt][ks], L[nt], 0, 0, 0);
          L[nt] = MFMA(Al[ks], wdh[nt][ks], L[nt], 0, 0, 0);
          L[nt] = MFMA(Ah[ks], wl, L[nt], 0, 0, 0);
        }
      // softmax (logits bounded; clamp is pure insurance) + stores
      #pragma unroll
      for (int rr = 0; rr < 4; ++rr) {
        float e0 = __expf(fminf(L[0][rr], 80.f));
        float e1 = __expf(fminf(L[1][rr], 80.f));
        float e2 = __expf(fminf(L[2][rr], 80.f));
        float e3 = __expf(fminf(L[3][rr], 80.f));
        float e4 = (n < 14) ? __expf(fminf(L[4][rr], 80.f)) : 0.0f;
        float sm = e0 + e1 + e2 + e3 + e4;
        sm += dppror<0x128>(sm);
        sm += dppror<0x124>(sm);
        sm += dppror<0x122>(sm);
        sm += dppror<0x121>(sm);
        float inv = __builtin_amdgcn_rcpf(sm);
        size_t grow = (size_t)blockbase + w * 16 + g * 4 + rr;
        float* orow = out + (grow * 25 + s) * 78;
        orow[n]      = e0 * inv;
        orow[16 + n] = e1 * inv;
        orow[32 + n] = e2 * inv;
        orow[48 + n] = e3 * inv;
        if (n < 14) orow[64 + n] = e4 * inv;
      }
    } else if (s < 24) {
      // gates: all 64 rows, this wave's jt col-slice
      #pragma unroll
      for (int mt = 0; mt < 4; ++mt) {
        f32x4 C0 = {bz, bz, bz, bz};
        f32x4 C1 = {brr, brr, brr, brr};
        f32x4 C2 = {bxh, bxh, bxh, bxh};
        f32x4 C3 = {bhh, bhh, bhh, bhh};
        #pragma unroll
        for (int ks = 0; ks < 2; ++ks) {
          bf16x8 Ah = *(const bf16x8*)(curHi + (mt * 16 + n) * HSTR + ks * 32 + g * 8);
          bf16x8 Al = *(const bf16x8*)(curLo + (mt * 16 + n) * HSTR + ks * 32 + g * 8);
          C0 = MFMA(Ah, Wh[0][ks], C0, 0, 0, 0);
          C0 = MFMA(Al, Wh[0][ks], C0, 0, 0, 0);
          C0 = MFMA(Ah, Wl[0][ks], C0, 0, 0, 0);
          C1 = MFMA(Ah, Wh[1][ks], C1, 0, 0, 0);
          C1 = MFMA(Al, Wh[1][ks], C1, 0, 0, 0);
          C1 = MFMA(Ah, Wl[1][ks], C1, 0, 0, 0);
          C2 = MFMA(Ah, Wh[2][ks], C2, 0, 0, 0);
          C2 = MFMA(Al, Wh[2][ks], C2, 0, 0, 0);
          C2 = MFMA(Ah, Wl[2][ks], C2, 0, 0, 0);
          C3 = MFMA(Ah, Wh[3][ks], C3, 0, 0, 0);
          C3 = MFMA(Al, Wh[3][ks], C3, 0, 0, 0);
          C3 = MFMA(Ah, Wl[3][ks], C3, 0, 0, 0);
        }
        #pragma unroll
        for (int rr = 0; rr < 4; ++rr) {
          float z  = fsig(C0[rr]);
          float rg = fsig(C1[rr]);
          float cand = ftanh2(C2[rr] + rg * C3[rr]);
          float hv = cand + z * (hold[mt * 4 + rr] - cand);
          hold[mt * 4 + rr] = hv;
          unsigned u = __float_as_uint(hv);
          int widx = (mt * 16 + g * 4 + rr) * HSTR + cb;
          nxtHi[widx] = (unsigned short)(u >> 16);
          nxtLo[widx] = bf16rne(hv - truncbf(hv));
        }
      }
    }
    if (s < 24) light_barrier();
  }
}

extern "C" void kernel_launch(void* const* d_in, const int* in_sizes, int n_in,
                              void* d_out, int out_size, void* d_ws, size_t ws_size,
                              hipStream_t stream) {
  const float* x   = (const float*)d_in[0];
  const float* H   = (const float*)d_in[1];
  const float* Wk  = (const float*)d_in[2];
  const float* Uk  = (const float*)d_in[3];
  const float* b   = (const float*)d_in[4];
  const float* Wd  = (const float*)d_in[5];
  const float* bd  = (const float*)d_in[6];
  float* out = (float*)d_out;
  (void)d_ws; (void)ws_size; (void)in_sizes; (void)n_in; (void)out_size;

  const int lds = 14336 * 4;  // 57344 B -> 2 blocks/CU
  vgru_all<<<dim3(512), dim3(TPB), lds, stream>>>(x, H, Wk, Uk, b, Wd, bd, out);
}

// Round 6
// 152.659 us; speedup vs baseline: 2.4571x; 2.4571x over previous
//
#include <hip/hip_runtime.h>

// VGRUd v6 — v4 structure + pre-split h planes + light barriers.
// 256 blocks x 512 thr (8 waves), 128 rows/block, launch_bounds(512,2).
// Wave w: gates for rows (w>>2)*64..+64, gate col-slice jt=w&3 (weights
//   persistent in VGPR/AGPR); logits for rows w*16..+16 (Wd-hi persistent,
//   Wd-lo streamed from LDS).
// h stored PRE-SPLIT in LDS as hi/lo bf16 planes in MFMA-frag layout
//   [mt][ks][g][n][8j] -> A-frags are single ds_read_b128, zero split VALU,
//   conflict-free (each 8-lane window covers all 32 banks).
// Main loop barrier = lgkmcnt(0)+s_barrier only (probs stores stay in flight).
// Step 1 (K=192) fused via 6 staged K=32 chunks (gate-remapped [Wk;Uk]).
// 3xbf16 MFMA emulation (hi*hi + lo*hi + hi*lo).

typedef short bf16x8 __attribute__((ext_vector_type(8)));
typedef float f32x4 __attribute__((ext_vector_type(4)));

#define TPB 512

__device__ __forceinline__ float fsig(float x) {
  return __builtin_amdgcn_rcpf(1.0f + __expf(-x));
}
__device__ __forceinline__ float ftanh2(float x) {
  return 1.0f - 2.0f * __builtin_amdgcn_rcpf(__expf(2.0f * x) + 1.0f);
}
template <int CTRL>
__device__ __forceinline__ float dppror(float x) {
  return __int_as_float(
      __builtin_amdgcn_update_dpp(0, __float_as_int(x), CTRL, 0xf, 0xf, true));
}
__device__ __forceinline__ unsigned pack_hi16(float a, float b) {
  return __builtin_amdgcn_perm(__float_as_uint(b), __float_as_uint(a), 0x07060302u);
}
__device__ __forceinline__ float truncbf(float a) {
  return __uint_as_float(__float_as_uint(a) & 0xffff0000u);
}
__device__ __forceinline__ unsigned short bf16rne(float f) {
  unsigned u = __float_as_uint(f);
  return (unsigned short)((u + 0x7fffu + ((u >> 16) & 1u)) >> 16);
}
__device__ __forceinline__ void split8(const float f[8], bf16x8& ah, bf16x8& al) {
  uint4 ph, pl;
  ph.x = pack_hi16(f[0], f[1]); ph.y = pack_hi16(f[2], f[3]);
  ph.z = pack_hi16(f[4], f[5]); ph.w = pack_hi16(f[6], f[7]);
  pl.x = pack_hi16(f[0] - truncbf(f[0]), f[1] - truncbf(f[1]));
  pl.y = pack_hi16(f[2] - truncbf(f[2]), f[3] - truncbf(f[3]));
  pl.z = pack_hi16(f[4] - truncbf(f[4]), f[5] - truncbf(f[5]));
  pl.w = pack_hi16(f[6] - truncbf(f[6]), f[7] - truncbf(f[7]));
  ah = __builtin_bit_cast(bf16x8, ph);
  al = __builtin_bit_cast(bf16x8, pl);
}
__device__ __forceinline__ void light_barrier() {
  __builtin_amdgcn_sched_barrier(0);
  asm volatile("s_waitcnt lgkmcnt(0)" ::: "memory");
  __builtin_amdgcn_s_barrier();
  __builtin_amdgcn_sched_barrier(0);
}

#define MFMA __builtin_amdgcn_mfma_f32_16x16x32_bf16

__global__ __launch_bounds__(TPB, 2) void vgru_all(
    const float* __restrict__ x, const float* __restrict__ Hin,
    const float* __restrict__ Wk, const float* __restrict__ Uk,
    const float* __restrict__ bias, const float* __restrict__ Wd,
    const float* __restrict__ bd, float* __restrict__ out)
{
  extern __shared__ float smem[];
  float* wdHi = smem;            // 10 frags x 64 lanes x 16B = 2560 f
  float* wdLo = smem + 2560;     // 2560 f
  unsigned short* hbase = (unsigned short*)(smem + 5120);
  // h buffer p (p=0,1): ush offset p*16384; hi [0,8192), lo [8192,16384)
  // element (mt,ks,g,n,j): off = (((mt*2+ks)*4+g)*16+n)*8 + j
  float* chkHi = smem + 13312;   // step-1 staging, aliases h buf1
  float* chkLo = smem + 17408;   // total 21504 floats = 86016 B

  const int tid  = threadIdx.x;
  const int lane = tid & 63, w = tid >> 6;
  const int g = lane >> 4, n = lane & 15;
  const int jt = w & 3;
  const int row0g = (w >> 2) * 64;      // gates rows base (local)
  const int blockbase = blockIdx.x * 128;
  const float* b0 = bias;
  const float* b1 = bias + 192;

  // ---- stage Wd frags (hi/lo planes) ----
  for (int idx = tid; idx < 640; idx += TPB) {
    int fr = idx >> 6, ln = idx & 63;
    int nt = fr >> 1, ks = fr & 1;
    int lg = ln >> 4, lnn = ln & 15;
    int c = nt * 16 + lnn;
    float f[8];
    #pragma unroll
    for (int j = 0; j < 8; ++j) {
      int k = ks * 32 + lg * 8 + j;
      f[j] = (c < 78) ? Wd[k * 78 + c] : 0.0f;
    }
    bf16x8 h8, l8; split8(f, h8, l8);
    ((bf16x8*)wdHi)[fr * 64 + ln] = h8;
    ((bf16x8*)wdLo)[fr * 64 + ln] = l8;
  }

  // per-lane gate biases (col cb)
  const int cb = jt * 16 + n;
  const float bz  = b0[cb] + b1[cb];
  const float brr = b0[64 + cb] + b1[64 + cb];
  const float bxh = b0[128 + cb];
  const float bhh = b1[128 + cb];

  // ---- step 1: h1 = gru(x, H), K=192 in 6 chunks of K=32 ----
  f32x4 G0[4][4];  // [mt][gate]
  #pragma unroll
  for (int mt = 0; mt < 4; ++mt) {
    G0[mt][0] = (f32x4){bz, bz, bz, bz};
    G0[mt][1] = (f32x4){brr, brr, brr, brr};
    G0[mt][2] = (f32x4){bxh, bxh, bxh, bxh};
    G0[mt][3] = (f32x4){bhh, bhh, bhh, bhh};
  }

  for (int t = 0; t < 6; ++t) {
    // stage chunk: stacked [Wk;Uk] rows t*32..+32, gate-remapped cols
    for (int idx = tid; idx < 1024; idx += TPB) {
      int fr = idx >> 6, ln = idx & 63;      // fr = col-tile 0..15
      int lg = ln >> 4, lnn = ln & 15;
      int c = fr * 16 + lnn;
      float f[8];
      #pragma unroll
      for (int j = 0; j < 8; ++j) {
        int k = t * 32 + lg * 8 + j;
        float v;
        if (k < 128) v = (c < 192) ? Wk[k * 192 + c] : 0.0f;
        else {
          int ku = k - 128;
          v = (c < 128) ? Uk[ku * 192 + c]
                        : ((c < 192) ? 0.0f : Uk[ku * 192 + 128 + (c - 192)]);
        }
        f[j] = v;
      }
      bf16x8 h8, l8; split8(f, h8, l8);
      ((bf16x8*)chkHi)[fr * 64 + ln] = h8;
      ((bf16x8*)chkLo)[fr * 64 + ln] = l8;
    }
    __syncthreads();
    {
      bf16x8 Ah[4], Al[4];
      #pragma unroll
      for (int mt = 0; mt < 4; ++mt) {
        const float* src = (t < 4)
            ? x + (size_t)(blockbase + row0g + mt * 16 + n) * 128 + t * 32 + g * 8
            : Hin + (size_t)(blockbase + row0g + mt * 16 + n) * 64 + (t - 4) * 32 + g * 8;
        float4 v0 = *(const float4*)src;
        float4 v1 = *(const float4*)(src + 4);
        float f[8] = {v0.x, v0.y, v0.z, v0.w, v1.x, v1.y, v1.z, v1.w};
        split8(f, Ah[mt], Al[mt]);
      }
      #pragma unroll
      for (int gg = 0; gg < 4; ++gg) {
        int ntb = gg * 4 + jt;
        bf16x8 wh = ((const bf16x8*)chkHi)[ntb * 64 + lane];
        bf16x8 wl = ((const bf16x8*)chkLo)[ntb * 64 + lane];
        #pragma unroll
        for (int mt = 0; mt < 4; ++mt) {
          G0[mt][gg] = MFMA(Ah[mt], wh, G0[mt][gg], 0, 0, 0);
          G0[mt][gg] = MFMA(Al[mt], wh, G0[mt][gg], 0, 0, 0);
          G0[mt][gg] = MFMA(Ah[mt], wl, G0[mt][gg], 0, 0, 0);
        }
      }
    }
    __syncthreads();
  }

  // step-1 epilogue: hold regs + pre-split h1 into buf0
  float hold[16];
  {
    unsigned short* h0Hi = hbase;
    unsigned short* h0Lo = hbase + 8192;
    const int ksw = jt >> 1;
    const int gw  = (jt * 2 + (n >> 3)) & 3;
    const int jw  = n & 7;
    #pragma unroll
    for (int mt = 0; mt < 4; ++mt) {
      int mtw = (w >> 2) * 4 + mt;
      #pragma unroll
      for (int rr = 0; rr < 4; ++rr) {
        int lrow = row0g + mt * 16 + g * 4 + rr;
        float h0 = Hin[(size_t)(blockbase + lrow) * 64 + cb];
        float z  = fsig(G0[mt][0][rr]);
        float rg = fsig(G0[mt][1][rr]);
        float cand = ftanh2(G0[mt][2][rr] + rg * G0[mt][3][rr]);
        float hv = cand + z * (h0 - cand);
        hold[mt * 4 + rr] = hv;
        int off = (((mtw * 2 + ksw) * 4 + gw) * 16 + (g * 4 + rr)) * 8 + jw;
        unsigned u = __float_as_uint(hv);
        h0Hi[off] = (unsigned short)(u >> 16);
        h0Lo[off] = bf16rne(hv - truncbf(hv));
      }
    }
  }

  // ---- persistent weights ----
  bf16x8 Wh[4][2], Wl[4][2];  // combined gate matrix, jt slice
  #pragma unroll
  for (int gg = 0; gg < 4; ++gg)
    #pragma unroll
    for (int ks = 0; ks < 2; ++ks) {
      int c = (gg * 4 + jt) * 16 + n;
      float f[8];
      #pragma unroll
      for (int j = 0; j < 8; ++j) {
        int k = ks * 32 + g * 8 + j;
        float v;
        if      (c < 128) v = Wk[k * 192 + c] + Uk[k * 192 + c];
        else if (c < 192) v = Wk[k * 192 + c];
        else              v = Uk[k * 192 + 128 + (c - 192)];
        f[j] = v;
      }
      split8(f, Wh[gg][ks], Wl[gg][ks]);
    }
  bf16x8 wdh[5][2];            // Wd hi persistent
  float bdv[5];
  #pragma unroll
  for (int nt = 0; nt < 5; ++nt) {
    #pragma unroll
    for (int ks = 0; ks < 2; ++ks)
      wdh[nt][ks] = ((const bf16x8*)wdHi)[(nt * 2 + ks) * 64 + lane];
    int c = nt * 16 + n;
    bdv[nt] = (c < 78) ? bd[c] : 0.0f;
  }
  __syncthreads();

  // ---- 25 iterations ----
  const int ksw = jt >> 1;
  const int gw  = (jt * 2 + (n >> 3)) & 3;
  const int jw  = n & 7;
  #pragma unroll 1
  for (int s = 0; s < 25; ++s) {
    const unsigned short* curHi = hbase + (s & 1) * 16384;
    const unsigned short* curLo = curHi + 8192;
    unsigned short* nxtHi = hbase + ((s + 1) & 1) * 16384;
    unsigned short* nxtLo = nxtHi + 8192;

    {  // logits for rows w*16..+16 (mt index = w)
      bf16x8 Ah[2], Al[2];
      #pragma unroll
      for (int ks = 0; ks < 2; ++ks) {
        int off = (((w * 2 + ks) * 4 + g) * 16 + n) * 8;
        Ah[ks] = *(const bf16x8*)(curHi + off);
        Al[ks] = *(const bf16x8*)(curLo + off);
      }
      f32x4 L[5];
      #pragma unroll
      for (int nt = 0; nt < 5; ++nt)
        L[nt] = (f32x4){bdv[nt], bdv[nt], bdv[nt], bdv[nt]};
      #pragma unroll
      for (int nt = 0; nt < 5; ++nt)
        #pragma unroll
        for (int ks = 0; ks < 2; ++ks) {
          bf16x8 wl = ((const bf16x8*)wdLo)[(nt * 2 + ks) * 64 + lane];
          L[nt] = MFMA(Ah[ks], wdh[nt][ks], L[nt], 0, 0, 0);
          L[nt] = MFMA(Al[ks], wdh[nt][ks], L[nt], 0, 0, 0);
          L[nt] = MFMA(Ah[ks], wl, L[nt], 0, 0, 0);
        }
      // softmax (no max-sub; logits bounded, clamp 60 insurance) + stores
      #pragma unroll
      for (int rr = 0; rr < 4; ++rr) {
        float e0 = __expf(fminf(L[0][rr], 60.f));
        float e1 = __expf(fminf(L[1][rr], 60.f));
        float e2 = __expf(fminf(L[2][rr], 60.f));
        float e3 = __expf(fminf(L[3][rr], 60.f));
        float e4 = (n < 14) ? __expf(fminf(L[4][rr], 60.f)) : 0.0f;
        float sm = e0 + e1 + e2 + e3 + e4;
        sm += dppror<0x128>(sm);
        sm += dppror<0x124>(sm);
        sm += dppror<0x122>(sm);
        sm += dppror<0x121>(sm);
        float inv = __builtin_amdgcn_rcpf(sm);
        size_t grow = (size_t)blockbase + w * 16 + g * 4 + rr;
        float* orow = out + (grow * 25 + s) * 78;
        orow[n]      = e0 * inv;
        orow[16 + n] = e1 * inv;
        orow[32 + n] = e2 * inv;
        orow[48 + n] = e3 * inv;
        if (n < 14) orow[64 + n] = e4 * inv;
      }
    }

    if (s < 24) {
      // gates: rows row0g..+64, this wave's jt col-slice
      #pragma unroll
      for (int mt = 0; mt < 4; ++mt) {
        int mtg = (w >> 2) * 4 + mt;
        f32x4 C0 = {bz, bz, bz, bz};
        f32x4 C1 = {brr, brr, brr, brr};
        f32x4 C2 = {bxh, bxh, bxh, bxh};
        f32x4 C3 = {bhh, bhh, bhh, bhh};
        #pragma unroll
        for (int ks = 0; ks < 2; ++ks) {
          int off = (((mtg * 2 + ks) * 4 + g) * 16 + n) * 8;
          bf16x8 Ah = *(const bf16x8*)(curHi + off);
          bf16x8 Al = *(const bf16x8*)(curLo + off);
          C0 = MFMA(Ah, Wh[0][ks], C0, 0, 0, 0);
          C0 = MFMA(Al, Wh[0][ks], C0, 0, 0, 0);
          C0 = MFMA(Ah, Wl[0][ks], C0, 0, 0, 0);
          C1 = MFMA(Ah, Wh[1][ks], C1, 0, 0, 0);
          C1 = MFMA(Al, Wh[1][ks], C1, 0, 0, 0);
          C1 = MFMA(Ah, Wl[1][ks], C1, 0, 0, 0);
          C2 = MFMA(Ah, Wh[2][ks], C2, 0, 0, 0);
          C2 = MFMA(Al, Wh[2][ks], C2, 0, 0, 0);
          C2 = MFMA(Ah, Wl[2][ks], C2, 0, 0, 0);
          C3 = MFMA(Ah, Wh[3][ks], C3, 0, 0, 0);
          C3 = MFMA(Al, Wh[3][ks], C3, 0, 0, 0);
          C3 = MFMA(Ah, Wl[3][ks], C3, 0, 0, 0);
        }
        #pragma unroll
        for (int rr = 0; rr < 4; ++rr) {
          float z  = fsig(C0[rr]);
          float rg = fsig(C1[rr]);
          float cand = ftanh2(C2[rr] + rg * C3[rr]);
          float hv = cand + z * (hold[mt * 4 + rr] - cand);
          hold[mt * 4 + rr] = hv;
          int off = (((mtg * 2 + ksw) * 4 + gw) * 16 + (g * 4 + rr)) * 8 + jw;
          unsigned u = __float_as_uint(hv);
          nxtHi[off] = (unsigned short)(u >> 16);
          nxtLo[off] = bf16rne(hv - truncbf(hv));
        }
      }
      light_barrier();
    }
  }
}

extern "C" void kernel_launch(void* const* d_in, const int* in_sizes, int n_in,
                              void* d_out, int out_size, void* d_ws, size_t ws_size,
                              hipStream_t stream) {
  const float* x   = (const float*)d_in[0];
  const float* H   = (const float*)d_in[1];
  const float* Wk  = (const float*)d_in[2];
  const float* Uk  = (const float*)d_in[3];
  const float* b   = (const float*)d_in[4];
  const float* Wd  = (const float*)d_in[5];
  const float* bd  = (const float*)d_in[6];
  float* out = (float*)d_out;
  (void)d_ws; (void)ws_size; (void)in_sizes; (void)n_in; (void)out_size;

  const int lds = 21504 * 4;  // 86016 B
  hipFuncSetAttribute((const void*)vgru_all,
                      hipFuncAttributeMaxDynamicSharedMemorySize, lds);
  vgru_all<<<dim3(256), dim3(TPB), lds, stream>>>(x, H, Wk, Uk, b, Wd, bd, out);
}